// Round 16
// baseline (78.104 us; speedup 1.0000x reference)
//
#include <hip/hip_runtime.h>
#include <hip/hip_bf16.h>

typedef __attribute__((ext_vector_type(8)))  short short8;
typedef __attribute__((ext_vector_type(4)))  short short4v;
typedef __attribute__((ext_vector_type(4)))  float f32x4;

static __device__ inline short f2bf(float f) {
    union { __hip_bfloat16 h; unsigned short u; } cv;
    cv.h = __float2bfloat16(f);
    return (short)cv.u;
}

typedef __attribute__((address_space(3))) void lds_void;
typedef const __attribute__((address_space(1))) void glob_void;
static __device__ inline void gl16(const void* g, void* l) {
    // global -> LDS direct copy, 16 B/lane (1 KiB/wave). LDS dest must be
    // wave-uniform base (+ lane*16 HW-added); global src is per-lane.
    __builtin_amdgcn_global_load_lds((glob_void*)g, (lds_void*)l, 16, 0, 0);
}

// ---------------------------------------------------------------------------
// Kernel 1: k_prep — ALL prep work in ONE dispatch. Narrow roles FIRST
// (R15: serial-tail fix, confirmed). Transpose block decode puts h in the
// LOW bits: co-resident blocks sweep 64 h values -> their 256B reads tile
// contiguous 16KB rows -> full HBM channel spread (R15: cbq-fastest decode
// made all concurrent reads hit the same 256B-offset-within-16KB-stride ->
// same channel subset -> 1.96 TB/s cap).
//   blocks [0,512)     : fold1 -> wd_frag
//   blocks [512,1024)  : fold2 -> wu_frag
//   blocks [1024,1544) : zero halo of xTc
//   blocks [1544,1577) : zero halo of tp2
//   block  1577        : bd_eff
//   blocks [1578,5674) : transpose (h fastest, then cbq, then b)
// ---------------------------------------------------------------------------
__global__ __launch_bounds__(256) void k_prep(const float* __restrict__ x,
                                              const float* __restrict__ f1,
                                              const float* __restrict__ f2,
                                              const float* __restrict__ wd,
                                              const float* __restrict__ bd,
                                              const float* __restrict__ wu,
                                              short* __restrict__ xTc,
                                              short* __restrict__ wd_frag,
                                              short* __restrict__ wu_frag,
                                              float* __restrict__ bd_eff,
                                              short* __restrict__ tp2) {
    __shared__ float lds[64][65];     // 16.6 KB
    int blk = blockIdx.x;
    int t = threadIdx.x;

    if (blk < 512) {
        // ---- fold1 role: wd_frag[b][ci16][kpos9][mt2][512], lane-linear ----
        int id = blk * 256 + t;
        int i = id & 511;
        int o = (id >> 9) & 31;
        int b = id >> 14;
        float acc[9];
        #pragma unroll
        for (int k = 0; k < 9; ++k) acc[k] = 0.f;
        for (int m = 0; m < 32; ++m) {
            float f = f1[(b * 32 + o) * 32 + m];
            const float* wrow = wd + ((size_t)m * 512 + i) * 9;
            #pragma unroll
            for (int k = 0; k < 9; ++k) acc[k] += f * wrow[k];
        }
        int ci = i >> 5, hi = (i >> 3) & 3, e = i & 7;
        int mt = o >> 4, lo = o & 15;
        #pragma unroll
        for (int k = 0; k < 9; ++k)
            wd_frag[(((size_t)(b * 16 + ci) * 9 + k) * 2 + mt) * 512
                    + hi * 128 + lo * 8 + e] = f2bf(acc[k]);
    } else if (blk < 1024) {
        // ---- fold2 role: wu_frag[b][kpos9][g32][512] ----
        int id = (blk - 512) * 256 + t;
        int c = id & 31;
        int O = (id >> 5) & 511;
        int b = id >> 14;
        float acc[9];
        #pragma unroll
        for (int k = 0; k < 9; ++k) acc[k] = 0.f;
        for (int m = 0; m < 32; ++m) {
            float f = f2[(b * 32 + m) * 32 + c];
            const float* wr = wu + ((size_t)O * 32 + m) * 9;
            #pragma unroll
            for (int k = 0; k < 9; ++k) acc[k] += wr[k] * f;
        }
        int g = O >> 4, lo = O & 15, hi = c >> 3, e = c & 7;
        #pragma unroll
        for (int k = 0; k < 9; ++k)
            wu_frag[((size_t)(b * 9 + k) * 32 + g) * 512 + lo * 32 + hi * 8 + e]
                = f2bf(acc[k]);
    } else if (blk < 1544) {
        // ---- zero halo of xTc: [64 img][66][66][64] ----
        int id = (blk - 1024) * 256 + t;
        if (id < 64 * 260 * 8) {
            int c8 = id % 8;
            int rest = id / 8;
            int px = rest % 260;
            int img = rest / 260;
            int row, col;
            if (px < 66)       { row = 0;  col = px; }
            else if (px < 132) { row = 65; col = px - 66; }
            else { int q = px - 132; row = 1 + (q >> 1); col = (q & 1) ? 65 : 0; }
            short8 z = {0, 0, 0, 0, 0, 0, 0, 0};
            *(short8*)(xTc + ((size_t)(img * 66 + row) * 66 + col) * 64 + c8 * 8) = z;
        }
    } else if (blk < 1577) {
        // ---- zero halo of tp2: [8 img][66][80][32] ----
        int id = (blk - 1544) * 256 + t;
        if (id < 8 * 260 * 4) {
            int c8 = id % 4;
            int rest = id / 4;
            int px = rest % 260;
            int img = rest / 260;
            int row, col;
            if (px < 66)       { row = 0;  col = px; }
            else if (px < 132) { row = 65; col = px - 66; }
            else { int q = px - 132; row = 1 + (q >> 1); col = (q & 1) ? 65 : 0; }
            short8 z = {0, 0, 0, 0, 0, 0, 0, 0};
            *(short8*)(tp2 + ((size_t)(img * 66 + row) * 80 + col) * 32 + c8 * 8) = z;
        }
    } else if (blk == 1577) {
        // ---- bd role ----
        int b = t >> 5, o = t & 31;
        float acc = 0.f;
        #pragma unroll
        for (int m = 0; m < 32; ++m) acc += f1[(b * 32 + o) * 32 + m] * bd[m];
        bd_eff[t] = acc;
    } else {
        // ---- transpose role: h FASTEST (HBM channel spread), then cbq, b ----
        int tb = blk - 1578;
        int h = tb & 63;
        int cbq = (tb >> 6) & 7;
        int b = tb >> 9;
        #pragma unroll
        for (int k = 0; k < 4; ++k) {
            int idx = k * 256 + t;          // (c, 4-float group)
            int c = idx >> 4, wq = idx & 15;
            f32x4 v = *(const f32x4*)(x + (((size_t)b * 512 + cbq * 64 + c) * 64 + h) * 64
                                        + wq * 4);
            lds[c][wq * 4 + 0] = v.x;
            lds[c][wq * 4 + 1] = v.y;
            lds[c][wq * 4 + 2] = v.z;
            lds[c][wq * 4 + 3] = v.w;
        }
        __syncthreads();
        // read phase: 512 jobs = (sl, w); lanes sweep 8 sl x 8 w-low:
        // bank = 8(sl%4)+wl+const -> 2-way only (free).
        #pragma unroll
        for (int k = 0; k < 2; ++k) {
            int j = k * 256 + t;
            int sl = j & 7;
            int wl = (j >> 3) & 7;
            int wh = j >> 6;                 // wave-uniform
            int w = wh * 8 + wl;
            short8 v;
            #pragma unroll
            for (int e = 0; e < 8; ++e) v[e] = f2bf(lds[sl * 8 + e][w]);
            int slotp = sl ^ ((w + 1) & 7);
            *(short8*)(xTc + (((size_t)(b * 8 + cbq) * 66 + (h + 1)) * 66 + (w + 1)) * 64
                           + slotp * 8) = v;
        }
    }
}

// ---------------------------------------------------------------------------
// Kernel 2: conv_down, K-split pipelined (unchanged from R10/R11).
// ---------------------------------------------------------------------------
__global__ __launch_bounds__(512) void k_conv_down(const char* __restrict__ xTc,
                                                   const char* __restrict__ wd_frag,
                                                   const float* __restrict__ bd_eff,
                                                   short* __restrict__ tp2) {
    __shared__ __align__(16) char xs[2][2][16896];   // [ks][buf][4r x 66c x 64B]
    __shared__ __align__(16) char as_[2][2][18432];  // [ks][buf][9 kpos][2 mt][1KB]
    int d = blockIdx.x;                // 256
    int nb = (d & 7) * 32 + (d >> 3);  // XCD <-> batch swizzle
    int b = nb >> 5, rp = nb & 31;
    int R0 = rp * 2;
    int t = threadIdx.x, lane = t & 63, wv = t >> 6;   // wv 0..7
    int ks = wv >> 2, lr = (wv >> 1) & 1, colh = wv & 1;
    int lo = lane & 15, hi = lane >> 4;

    const char* wdb = wd_frag + (size_t)(b * 16) * 18432;
    const char* xbb = xTc + (size_t)(b * 8) * 557568;

#define STAGE_CD(ci, bf)                                                         \
    {                                                                            \
        const int cc0 = (ci);                                                    \
        const int half4 = (cc0 & 1) * 4;                                         \
        const char* xpl0 = xbb + (size_t)(cc0 >> 1) * 557568;                    \
        const char* xpl1 = xpl0 + (size_t)4 * 557568;                            \
        const char* apl0 = wdb + (size_t)cc0 * 18432;                            \
        const char* apl1 = apl0 + (size_t)8 * 18432;                             \
        _Pragma("unroll")                                                        \
        for (int i2 = 0; i2 < 9; ++i2) {                                         \
            int j = wv * 9 + i2;                                                 \
            if (j >= 70) j -= 70;                                                \
            if (j < 34) {                       /* x job */                      \
                int kss = (j >= 17);                                             \
                int jj = kss ? j - 17 : j;                                       \
                int off = (jj < 16) ? jj * 1024 : 15872;                         \
                int dd = off + (lane << 4);                                      \
                int r = dd / 4224;                                               \
                int rem = dd - r * 4224;                                         \
                int col = rem >> 6;                                              \
                int s4 = (rem >> 4) & 3;                                         \
                int slot = (half4 + (s4 ^ ((col >> 1) & 3))) ^ (col & 7);        \
                gl16((kss ? xpl1 : xpl0)                                         \
                         + ((size_t)(R0 + r) * 66 + col) * 128 + (slot << 4),    \
                     xs[kss][bf] + off);                                         \
            } else {                            /* A job */                      \
                int kss = (j >= 52);                                             \
                int jj = kss ? j - 52 : j - 34;                                  \
                gl16((kss ? apl1 : apl0) + jj * 1024 + (lane << 4),              \
                     as_[kss][bf] + jj * 1024);                                  \
            }                                                                    \
        }                                                                        \
    }

    f32x4 acc[2][2] = {};

    STAGE_CD(0, 0);

    #pragma unroll
    for (int ci = 0; ci < 8; ++ci) {
        int bf = ci & 1;
        if (ci < 7) {
            STAGE_CD(ci + 1, bf ^ 1);
            asm volatile("s_waitcnt vmcnt(9)" ::: "memory");
        } else {
            asm volatile("s_waitcnt vmcnt(0)" ::: "memory");
        }
        __builtin_amdgcn_sched_barrier(0);
        __builtin_amdgcn_s_barrier();
        __builtin_amdgcn_sched_barrier(0);

        const char* xb = xs[ks][bf];
        const char* ab = as_[ks][bf];
        #pragma unroll
        for (int kh = 0; kh < 3; ++kh) {
            #pragma unroll
            for (int kw = 0; kw < 3; ++kw) {
                const int kpos = kh * 3 + kw;
                short8 a0 = *(const short8*)(ab + (kpos * 2 + 0) * 1024 + (lane << 4));
                short8 a1 = *(const short8*)(ab + (kpos * 2 + 1) * 1024 + (lane << 4));
                int row = lr + kh;
                int g0 = colh * 32 + lo + kw;
                int g1 = g0 + 16;
                short8 b0 = *(const short8*)(xb + ((row * 66 + g0) << 6)
                                                + ((hi ^ ((g0 >> 1) & 3)) << 4));
                short8 b1 = *(const short8*)(xb + ((row * 66 + g1) << 6)
                                                + ((hi ^ ((g1 >> 1) & 3)) << 4));
                acc[0][0] = __builtin_amdgcn_mfma_f32_16x16x32_bf16(a0, b0, acc[0][0], 0, 0, 0);
                acc[0][1] = __builtin_amdgcn_mfma_f32_16x16x32_bf16(a0, b1, acc[0][1], 0, 0, 0);
                acc[1][0] = __builtin_amdgcn_mfma_f32_16x16x32_bf16(a1, b0, acc[1][0], 0, 0, 0);
                acc[1][1] = __builtin_amdgcn_mfma_f32_16x16x32_bf16(a1, b1, acc[1][1], 0, 0, 0);
            }
        }
        __builtin_amdgcn_sched_barrier(0);
        __builtin_amdgcn_s_barrier();
    }
#undef STAGE_CD

    // cross-wave K-reduce via LDS scratch (all gl16 drained by peeled vmcnt(0)).
    char* scr = &xs[1][0][0];
    if (ks == 1) {
        char* p = scr + (wv & 3) * 4096 + lane * 64;
        *(f32x4*)(p +  0) = acc[0][0];
        *(f32x4*)(p + 16) = acc[0][1];
        *(f32x4*)(p + 32) = acc[1][0];
        *(f32x4*)(p + 48) = acc[1][1];
    }
    __syncthreads();
    if (ks == 0) {
        const char* p = scr + (wv & 3) * 4096 + lane * 64;
        acc[0][0] += *(const f32x4*)(p +  0);
        acc[0][1] += *(const f32x4*)(p + 16);
        acc[1][0] += *(const f32x4*)(p + 32);
        acc[1][1] += *(const f32x4*)(p + 48);

        int h = R0 + lr;
        #pragma unroll
        for (int nt = 0; nt < 2; ++nt) {
            int colp = colh * 32 + nt * 16 + lo + 1;
            short* ob = tp2 + ((size_t)(b * 66 + h + 1) * 80 + colp) * 32;
            #pragma unroll
            for (int mt = 0; mt < 2; ++mt) {
                f32x4 bd4 = *(const f32x4*)(bd_eff + b * 32 + mt * 16 + hi * 4);
                short4v sv;
                #pragma unroll
                for (int j = 0; j < 4; ++j) {
                    float f = acc[mt][nt][j] + bd4[j];
                    f = f > 0.f ? f : 0.2f * f;
                    sv[j] = f2bf(f);
                }
                int sl = mt * 2 + (hi >> 1);
                int slp = sl ^ (colp & 3);
                *(short4v*)(ob + slp * 8 + (hi & 1) * 4) = sv;
            }
        }
    }
}

// ---------------------------------------------------------------------------
// Kernel 3: conv_up + residual, A-staged pipeline (unchanged from R11).
// ---------------------------------------------------------------------------
__global__ __launch_bounds__(256, 3) void k_conv_up(const short* __restrict__ tp2,
                                                    const short* __restrict__ wu_frag,
                                                    const float* __restrict__ content,
                                                    const float* __restrict__ bu,
                                                    float* __restrict__ out) {
    __shared__ __align__(16) short tl[10240];     // 4 x 80 x 32
    __shared__ __align__(16) char au[3][8192];    // [buf][8 g][1KB frag]
    int d = blockIdx.x;                 // 1024
    int nb = (d & 7) * 128 + (d >> 3);  // XCD x <-> batch x
    int b = nb >> 7, ocq = (nb >> 5) & 3, hb = nb & 31;
    int t = threadIdx.x, lane = t & 63, wv = t >> 6;
    int lr = wv >> 1, oh = wv & 1;
    int lo = lane & 15, hi = lane >> 4;
    int Ob = ocq * 128 + oh * 64;
    int R0 = 2 * hb;

    const char* sbase = (const char*)tp2 + ((size_t)(b * 66 + R0) * 80) * 64;
    #pragma unroll
    for (int i = 0; i < 5; ++i)
        gl16(sbase + (wv * 5 + i) * 1024 + lane * 16, (char*)tl + (wv * 5 + i) * 1024);

    // A source: g-frags [ocq*8 .. ocq*8+8) per kpos; kpos stride = 32 KB.
    const char* abase = (const char*)wu_frag + ((size_t)(b * 9) * 32 + ocq * 8) * 1024;
    #pragma unroll
    for (int k0 = 0; k0 < 2; ++k0)        // prologue: stage A[0], A[1]
        #pragma unroll
        for (int i = 0; i < 2; ++i)
            gl16(abase + (size_t)k0 * 32768 + (wv * 2 + i) * 1024 + lane * 16,
                 au[k0] + (wv * 2 + i) * 1024);

    asm volatile("s_waitcnt vmcnt(0)" ::: "memory");
    __builtin_amdgcn_sched_barrier(0);
    __builtin_amdgcn_s_barrier();
    __builtin_amdgcn_sched_barrier(0);

    f32x4 acc[4][4] = {};
    const int aoff = oh * 4096 + lo * 64 + hi * 16;   // wave's byte base in au[]

    #pragma unroll
    for (int kh = 0; kh < 3; ++kh) {
        #pragma unroll
        for (int kw = 0; kw < 3; ++kw) {
            const int kpos = kh * 3 + kw;
            if (kpos < 7) {
                #pragma unroll
                for (int i = 0; i < 2; ++i)
                    gl16(abase + (size_t)(kpos + 2) * 32768 + (wv * 2 + i) * 1024
                             + lane * 16,
                         au[(kpos + 2) % 3] + (wv * 2 + i) * 1024);
                asm volatile("s_waitcnt vmcnt(4)" ::: "memory");
            } else if (kpos == 7) {
                asm volatile("s_waitcnt vmcnt(2)" ::: "memory");
            } else {
                asm volatile("s_waitcnt vmcnt(0)" ::: "memory");
            }
            __builtin_amdgcn_sched_barrier(0);
            __builtin_amdgcn_s_barrier();
            __builtin_amdgcn_sched_barrier(0);

            const char* ab = au[kpos % 3];
            short8 bf0, bf1, bf2, bf3;
            #pragma unroll
            for (int nt = 0; nt < 4; ++nt) {
                int g = nt * 16 + lo + kw;                 // padded col 0..65
                short8 bf = *(const short8*)(tl + ((lr + kh) * 80 + g) * 32
                                                + ((hi ^ (g & 3)) << 3));
                if (nt == 0) bf0 = bf; else if (nt == 1) bf1 = bf;
                else if (nt == 2) bf2 = bf; else bf3 = bf;
            }
            #pragma unroll
            for (int mt = 0; mt < 4; ++mt) {
                short8 af = *(const short8*)(ab + mt * 1024 + aoff);
                acc[mt][0] = __builtin_amdgcn_mfma_f32_16x16x32_bf16(af, bf0, acc[mt][0], 0, 0, 0);
                acc[mt][1] = __builtin_amdgcn_mfma_f32_16x16x32_bf16(af, bf1, acc[mt][1], 0, 0, 0);
                acc[mt][2] = __builtin_amdgcn_mfma_f32_16x16x32_bf16(af, bf2, acc[mt][2], 0, 0, 0);
                acc[mt][3] = __builtin_amdgcn_mfma_f32_16x16x32_bf16(af, bf3, acc[mt][3], 0, 0, 0);
            }
            __builtin_amdgcn_sched_barrier(0);
            __builtin_amdgcn_s_barrier();
        }
    }

    int h = R0 + lr;
    #pragma unroll
    for (int mt = 0; mt < 4; ++mt) {
        f32x4 bu4 = *(const f32x4*)(bu + Ob + mt * 16 + hi * 4);
        #pragma unroll
        for (int nt = 0; nt < 4; ++nt) {
            int px = nt * 16 + lo;
            #pragma unroll
            for (int j = 0; j < 4; ++j) {
                int O = Ob + mt * 16 + hi * 4 + j;
                size_t gidx = (((size_t)(b * 512 + O) * 64) + h) * 64 + px;
                out[gidx] = acc[mt][nt][j] + content[gidx] + bu4[j];
            }
        }
    }
}

// ---------------------------------------------------------------------------
extern "C" void kernel_launch(void* const* d_in, const int* in_sizes, int n_in,
                              void* d_out, int out_size, void* d_ws, size_t ws_size,
                              hipStream_t stream) {
    const float* content = (const float*)d_in[0];
    const float* f1      = (const float*)d_in[1];
    const float* f2      = (const float*)d_in[2];
    const float* wd      = (const float*)d_in[3];
    const float* bd      = (const float*)d_in[4];
    const float* wu      = (const float*)d_in[5];
    const float* bu      = (const float*)d_in[6];
    float* out = (float*)d_out;

    char* ws = (char*)d_ws;
    // layout (bytes):
    //   xTc    [8][8][66][66][64] bf16 : 35,684,352
    //   wd_frag                        :  2,359,296
    //   wu_frag                        :  2,359,296
    //   bd_eff                         :      1,024
    //   tp2    [8][66][80][32] bf16    :  2,703,360   (total ~43.1 MiB)
    short* xTc     = (short*)(ws);
    short* wd_frag = (short*)(ws + 35684352);
    short* wu_frag = (short*)(ws + 38043648);
    float* bd_eff  = (float*)(ws + 40402944);
    short* tp2     = (short*)(ws + 40403968);

    k_prep     <<<dim3(5674), dim3(256), 0, stream>>>(content, f1, f2, wd, bd, wu,
                                                      xTc, wd_frag, wu_frag,
                                                      bd_eff, tp2);
    k_conv_down<<<dim3(256),  dim3(512), 0, stream>>>((const char*)xTc,
                                                      (const char*)wd_frag,
                                                      bd_eff, tp2);
    k_conv_up  <<<dim3(1024), dim3(256), 0, stream>>>(tp2, wu_frag, content, bu, out);
}

// Round 17
// 76.290 us; speedup vs baseline: 1.0238x; 1.0238x over previous
//
#include <hip/hip_runtime.h>
#include <hip/hip_bf16.h>

typedef __attribute__((ext_vector_type(8)))  short short8;
typedef __attribute__((ext_vector_type(4)))  short short4v;
typedef __attribute__((ext_vector_type(4)))  float f32x4;

static __device__ inline short f2bf(float f) {
    union { __hip_bfloat16 h; unsigned short u; } cv;
    cv.h = __float2bfloat16(f);
    return (short)cv.u;
}

typedef __attribute__((address_space(3))) void lds_void;
typedef const __attribute__((address_space(1))) void glob_void;
static __device__ inline void gl16(const void* g, void* l) {
    // global -> LDS direct copy, 16 B/lane (1 KiB/wave). LDS dest must be
    // wave-uniform base (+ lane*16 HW-added); global src is per-lane.
    __builtin_amdgcn_global_load_lds((glob_void*)g, (lds_void*)l, 16, 0, 0);
}

// ---------------------------------------------------------------------------
// Kernel 1: k_prep — ALL prep work in ONE dispatch.
// R12-R16 lesson: the transpose-as-4096-tiny-blocks was BLOCK-CHURN bound
// (each block: 4 loads -> full-drain barrier -> store -> exit; ~900cyc cold
// HBM latency + launch overhead paid per 2k-cycle block; all pipes <10%).
// Fix: 512 LONG-LIVED transpose blocks, each looping 8 channel-group tiles
// with a reg-staged pipeline (issue next tile's loads under current tile's
// convert+store; raw s_barrier + counted vmcnt so barriers never drain the
// prefetch). Longest-job-first: transpose blocks at the FRONT.
//   blocks [0,512)     : transpose (fat, 8 tiles each)
//   blocks [512,1024)  : fold1 -> wd_frag
//   blocks [1024,1536) : fold2 -> wu_frag
//   blocks [1536,2056) : zero halo of xTc
//   blocks [2056,2089) : zero halo of tp2
//   block  2089        : bd_eff
// ---------------------------------------------------------------------------
__global__ __launch_bounds__(256) void k_prep(const float* __restrict__ x,
                                              const float* __restrict__ f1,
                                              const float* __restrict__ f2,
                                              const float* __restrict__ wd,
                                              const float* __restrict__ bd,
                                              const float* __restrict__ wu,
                                              short* __restrict__ xTc,
                                              short* __restrict__ wd_frag,
                                              short* __restrict__ wu_frag,
                                              float* __restrict__ bd_eff,
                                              short* __restrict__ tp2) {
    __shared__ float lds[64][65];     // 16.6 KB -> 8 blocks/CU
    int blk = blockIdx.x;
    int t = threadIdx.x;

    if (blk < 512) {
        // ---- transpose role: fat block = (b, h); loop cbq = 0..7 ----
        int h = blk & 63, b = blk >> 6;
        int cr = t >> 4, wq = t & 15;          // row-within-16, 4-float group
        const float* xb = x + ((size_t)h) * 64 + (size_t)wq * 4;
        // per-tile load address: xb + (b*512 + cbq*64 + k*16 + cr) * 4096
        f32x4 r0, r1, r2, r3;
        {
            const float* p = xb + ((size_t)(b * 512) + cr) * 4096;
            r0 = *(const f32x4*)(p);
            r1 = *(const f32x4*)(p + 16 * 4096);
            r2 = *(const f32x4*)(p + 32 * 4096);
            r3 = *(const f32x4*)(p + 48 * 4096);
        }
        for (int cb = 0; cb < 8; ++cb) {
            // loads for tile cb have landed; prev stores drained too
            asm volatile("s_waitcnt vmcnt(0)" ::: "memory");
            __builtin_amdgcn_sched_barrier(0);
            lds[ 0 + cr][wq * 4 + 0] = r0.x; lds[ 0 + cr][wq * 4 + 1] = r0.y;
            lds[ 0 + cr][wq * 4 + 2] = r0.z; lds[ 0 + cr][wq * 4 + 3] = r0.w;
            lds[16 + cr][wq * 4 + 0] = r1.x; lds[16 + cr][wq * 4 + 1] = r1.y;
            lds[16 + cr][wq * 4 + 2] = r1.z; lds[16 + cr][wq * 4 + 3] = r1.w;
            lds[32 + cr][wq * 4 + 0] = r2.x; lds[32 + cr][wq * 4 + 1] = r2.y;
            lds[32 + cr][wq * 4 + 2] = r2.z; lds[32 + cr][wq * 4 + 3] = r2.w;
            lds[48 + cr][wq * 4 + 0] = r3.x; lds[48 + cr][wq * 4 + 1] = r3.y;
            lds[48 + cr][wq * 4 + 2] = r3.z; lds[48 + cr][wq * 4 + 3] = r3.w;
            // issue next tile's loads (hidden under the read phase below)
            if (cb < 7) {
                const float* p = xb + ((size_t)(b * 512 + (cb + 1) * 64) + cr) * 4096;
                r0 = *(const f32x4*)(p);
                r1 = *(const f32x4*)(p + 16 * 4096);
                r2 = *(const f32x4*)(p + 32 * 4096);
                r3 = *(const f32x4*)(p + 48 * 4096);
            }
            asm volatile("s_waitcnt lgkmcnt(0)" ::: "memory");
            __builtin_amdgcn_sched_barrier(0);
            __builtin_amdgcn_s_barrier();
            __builtin_amdgcn_sched_barrier(0);
            // read phase: 512 jobs = (sl, w); lanes sweep 8 sl x 8 w-low:
            // bank = 8*sl + wl + const (mod 32) -> 2-way only (free).
            #pragma unroll
            for (int k = 0; k < 2; ++k) {
                int j = k * 256 + t;
                int sl = j & 7;
                int wl = (j >> 3) & 7;
                int wh = j >> 6;                 // wave-uniform
                int w = wh * 8 + wl;
                short8 v;
                #pragma unroll
                for (int e = 0; e < 8; ++e) v[e] = f2bf(lds[sl * 8 + e][w]);
                int slotp = sl ^ ((w + 1) & 7);
                *(short8*)(xTc + (((size_t)(b * 8 + cb) * 66 + (h + 1)) * 66 + (w + 1)) * 64
                               + slotp * 8) = v;
            }
            __builtin_amdgcn_s_barrier();       // reads done before next writes
        }
    } else if (blk < 1024) {
        // ---- fold1 role: wd_frag[b][ci16][kpos9][mt2][512], lane-linear ----
        int id = (blk - 512) * 256 + t;
        int i = id & 511;
        int o = (id >> 9) & 31;
        int b = id >> 14;
        float acc[9];
        #pragma unroll
        for (int k = 0; k < 9; ++k) acc[k] = 0.f;
        for (int m = 0; m < 32; ++m) {
            float f = f1[(b * 32 + o) * 32 + m];
            const float* wrow = wd + ((size_t)m * 512 + i) * 9;
            #pragma unroll
            for (int k = 0; k < 9; ++k) acc[k] += f * wrow[k];
        }
        int ci = i >> 5, hi = (i >> 3) & 3, e = i & 7;
        int mt = o >> 4, lo = o & 15;
        #pragma unroll
        for (int k = 0; k < 9; ++k)
            wd_frag[(((size_t)(b * 16 + ci) * 9 + k) * 2 + mt) * 512
                    + hi * 128 + lo * 8 + e] = f2bf(acc[k]);
    } else if (blk < 1536) {
        // ---- fold2 role: wu_frag[b][kpos9][g32][512] ----
        int id = (blk - 1024) * 256 + t;
        int c = id & 31;
        int O = (id >> 5) & 511;
        int b = id >> 14;
        float acc[9];
        #pragma unroll
        for (int k = 0; k < 9; ++k) acc[k] = 0.f;
        for (int m = 0; m < 32; ++m) {
            float f = f2[(b * 32 + m) * 32 + c];
            const float* wr = wu + ((size_t)O * 32 + m) * 9;
            #pragma unroll
            for (int k = 0; k < 9; ++k) acc[k] += wr[k] * f;
        }
        int g = O >> 4, lo = O & 15, hi = c >> 3, e = c & 7;
        #pragma unroll
        for (int k = 0; k < 9; ++k)
            wu_frag[((size_t)(b * 9 + k) * 32 + g) * 512 + lo * 32 + hi * 8 + e]
                = f2bf(acc[k]);
    } else if (blk < 2056) {
        // ---- zero halo of xTc: [64 img][66][66][64] ----
        int id = (blk - 1536) * 256 + t;
        if (id < 64 * 260 * 8) {
            int c8 = id % 8;
            int rest = id / 8;
            int px = rest % 260;
            int img = rest / 260;
            int row, col;
            if (px < 66)       { row = 0;  col = px; }
            else if (px < 132) { row = 65; col = px - 66; }
            else { int q = px - 132; row = 1 + (q >> 1); col = (q & 1) ? 65 : 0; }
            short8 z = {0, 0, 0, 0, 0, 0, 0, 0};
            *(short8*)(xTc + ((size_t)(img * 66 + row) * 66 + col) * 64 + c8 * 8) = z;
        }
    } else if (blk < 2089) {
        // ---- zero halo of tp2: [8 img][66][80][32] ----
        int id = (blk - 2056) * 256 + t;
        if (id < 8 * 260 * 4) {
            int c8 = id % 4;
            int rest = id / 4;
            int px = rest % 260;
            int img = rest / 260;
            int row, col;
            if (px < 66)       { row = 0;  col = px; }
            else if (px < 132) { row = 65; col = px - 66; }
            else { int q = px - 132; row = 1 + (q >> 1); col = (q & 1) ? 65 : 0; }
            short8 z = {0, 0, 0, 0, 0, 0, 0, 0};
            *(short8*)(tp2 + ((size_t)(img * 66 + row) * 80 + col) * 32 + c8 * 8) = z;
        }
    } else {
        // ---- bd role ----
        int b = t >> 5, o = t & 31;
        float acc = 0.f;
        #pragma unroll
        for (int m = 0; m < 32; ++m) acc += f1[(b * 32 + o) * 32 + m] * bd[m];
        bd_eff[t] = acc;
    }
}

// ---------------------------------------------------------------------------
// Kernel 2: conv_down, K-split pipelined (unchanged from R10/R11).
// ---------------------------------------------------------------------------
__global__ __launch_bounds__(512) void k_conv_down(const char* __restrict__ xTc,
                                                   const char* __restrict__ wd_frag,
                                                   const float* __restrict__ bd_eff,
                                                   short* __restrict__ tp2) {
    __shared__ __align__(16) char xs[2][2][16896];   // [ks][buf][4r x 66c x 64B]
    __shared__ __align__(16) char as_[2][2][18432];  // [ks][buf][9 kpos][2 mt][1KB]
    int d = blockIdx.x;                // 256
    int nb = (d & 7) * 32 + (d >> 3);  // XCD <-> batch swizzle
    int b = nb >> 5, rp = nb & 31;
    int R0 = rp * 2;
    int t = threadIdx.x, lane = t & 63, wv = t >> 6;   // wv 0..7
    int ks = wv >> 2, lr = (wv >> 1) & 1, colh = wv & 1;
    int lo = lane & 15, hi = lane >> 4;

    const char* wdb = wd_frag + (size_t)(b * 16) * 18432;
    const char* xbb = xTc + (size_t)(b * 8) * 557568;

#define STAGE_CD(ci, bf)                                                         \
    {                                                                            \
        const int cc0 = (ci);                                                    \
        const int half4 = (cc0 & 1) * 4;                                         \
        const char* xpl0 = xbb + (size_t)(cc0 >> 1) * 557568;                    \
        const char* xpl1 = xpl0 + (size_t)4 * 557568;                            \
        const char* apl0 = wdb + (size_t)cc0 * 18432;                            \
        const char* apl1 = apl0 + (size_t)8 * 18432;                             \
        _Pragma("unroll")                                                        \
        for (int i2 = 0; i2 < 9; ++i2) {                                         \
            int j = wv * 9 + i2;                                                 \
            if (j >= 70) j -= 70;                                                \
            if (j < 34) {                       /* x job */                      \
                int kss = (j >= 17);                                             \
                int jj = kss ? j - 17 : j;                                       \
                int off = (jj < 16) ? jj * 1024 : 15872;                         \
                int dd = off + (lane << 4);                                      \
                int r = dd / 4224;                                               \
                int rem = dd - r * 4224;                                         \
                int col = rem >> 6;                                              \
                int s4 = (rem >> 4) & 3;                                         \
                int slot = (half4 + (s4 ^ ((col >> 1) & 3))) ^ (col & 7);        \
                gl16((kss ? xpl1 : xpl0)                                         \
                         + ((size_t)(R0 + r) * 66 + col) * 128 + (slot << 4),    \
                     xs[kss][bf] + off);                                         \
            } else {                            /* A job */                      \
                int kss = (j >= 52);                                             \
                int jj = kss ? j - 52 : j - 34;                                  \
                gl16((kss ? apl1 : apl0) + jj * 1024 + (lane << 4),              \
                     as_[kss][bf] + jj * 1024);                                  \
            }                                                                    \
        }                                                                        \
    }

    f32x4 acc[2][2] = {};

    STAGE_CD(0, 0);

    #pragma unroll
    for (int ci = 0; ci < 8; ++ci) {
        int bf = ci & 1;
        if (ci < 7) {
            STAGE_CD(ci + 1, bf ^ 1);
            asm volatile("s_waitcnt vmcnt(9)" ::: "memory");
        } else {
            asm volatile("s_waitcnt vmcnt(0)" ::: "memory");
        }
        __builtin_amdgcn_sched_barrier(0);
        __builtin_amdgcn_s_barrier();
        __builtin_amdgcn_sched_barrier(0);

        const char* xb = xs[ks][bf];
        const char* ab = as_[ks][bf];
        #pragma unroll
        for (int kh = 0; kh < 3; ++kh) {
            #pragma unroll
            for (int kw = 0; kw < 3; ++kw) {
                const int kpos = kh * 3 + kw;
                short8 a0 = *(const short8*)(ab + (kpos * 2 + 0) * 1024 + (lane << 4));
                short8 a1 = *(const short8*)(ab + (kpos * 2 + 1) * 1024 + (lane << 4));
                int row = lr + kh;
                int g0 = colh * 32 + lo + kw;
                int g1 = g0 + 16;
                short8 b0 = *(const short8*)(xb + ((row * 66 + g0) << 6)
                                                + ((hi ^ ((g0 >> 1) & 3)) << 4));
                short8 b1 = *(const short8*)(xb + ((row * 66 + g1) << 6)
                                                + ((hi ^ ((g1 >> 1) & 3)) << 4));
                acc[0][0] = __builtin_amdgcn_mfma_f32_16x16x32_bf16(a0, b0, acc[0][0], 0, 0, 0);
                acc[0][1] = __builtin_amdgcn_mfma_f32_16x16x32_bf16(a0, b1, acc[0][1], 0, 0, 0);
                acc[1][0] = __builtin_amdgcn_mfma_f32_16x16x32_bf16(a1, b0, acc[1][0], 0, 0, 0);
                acc[1][1] = __builtin_amdgcn_mfma_f32_16x16x32_bf16(a1, b1, acc[1][1], 0, 0, 0);
            }
        }
        __builtin_amdgcn_sched_barrier(0);
        __builtin_amdgcn_s_barrier();
    }
#undef STAGE_CD

    // cross-wave K-reduce via LDS scratch (all gl16 drained by peeled vmcnt(0)).
    char* scr = &xs[1][0][0];
    if (ks == 1) {
        char* p = scr + (wv & 3) * 4096 + lane * 64;
        *(f32x4*)(p +  0) = acc[0][0];
        *(f32x4*)(p + 16) = acc[0][1];
        *(f32x4*)(p + 32) = acc[1][0];
        *(f32x4*)(p + 48) = acc[1][1];
    }
    __syncthreads();
    if (ks == 0) {
        const char* p = scr + (wv & 3) * 4096 + lane * 64;
        acc[0][0] += *(const f32x4*)(p +  0);
        acc[0][1] += *(const f32x4*)(p + 16);
        acc[1][0] += *(const f32x4*)(p + 32);
        acc[1][1] += *(const f32x4*)(p + 48);

        int h = R0 + lr;
        #pragma unroll
        for (int nt = 0; nt < 2; ++nt) {
            int colp = colh * 32 + nt * 16 + lo + 1;
            short* ob = tp2 + ((size_t)(b * 66 + h + 1) * 80 + colp) * 32;
            #pragma unroll
            for (int mt = 0; mt < 2; ++mt) {
                f32x4 bd4 = *(const f32x4*)(bd_eff + b * 32 + mt * 16 + hi * 4);
                short4v sv;
                #pragma unroll
                for (int j = 0; j < 4; ++j) {
                    float f = acc[mt][nt][j] + bd4[j];
                    f = f > 0.f ? f : 0.2f * f;
                    sv[j] = f2bf(f);
                }
                int sl = mt * 2 + (hi >> 1);
                int slp = sl ^ (colp & 3);
                *(short4v*)(ob + slp * 8 + (hi & 1) * 4) = sv;
            }
        }
    }
}

// ---------------------------------------------------------------------------
// Kernel 3: conv_up + residual, A-staged pipeline (unchanged from R11).
// ---------------------------------------------------------------------------
__global__ __launch_bounds__(256, 3) void k_conv_up(const short* __restrict__ tp2,
                                                    const short* __restrict__ wu_frag,
                                                    const float* __restrict__ content,
                                                    const float* __restrict__ bu,
                                                    float* __restrict__ out) {
    __shared__ __align__(16) short tl[10240];     // 4 x 80 x 32
    __shared__ __align__(16) char au[3][8192];    // [buf][8 g][1KB frag]
    int d = blockIdx.x;                 // 1024
    int nb = (d & 7) * 128 + (d >> 3);  // XCD x <-> batch x
    int b = nb >> 7, ocq = (nb >> 5) & 3, hb = nb & 31;
    int t = threadIdx.x, lane = t & 63, wv = t >> 6;
    int lr = wv >> 1, oh = wv & 1;
    int lo = lane & 15, hi = lane >> 4;
    int Ob = ocq * 128 + oh * 64;
    int R0 = 2 * hb;

    const char* sbase = (const char*)tp2 + ((size_t)(b * 66 + R0) * 80) * 64;
    #pragma unroll
    for (int i = 0; i < 5; ++i)
        gl16(sbase + (wv * 5 + i) * 1024 + lane * 16, (char*)tl + (wv * 5 + i) * 1024);

    // A source: g-frags [ocq*8 .. ocq*8+8) per kpos; kpos stride = 32 KB.
    const char* abase = (const char*)wu_frag + ((size_t)(b * 9) * 32 + ocq * 8) * 1024;
    #pragma unroll
    for (int k0 = 0; k0 < 2; ++k0)        // prologue: stage A[0], A[1]
        #pragma unroll
        for (int i = 0; i < 2; ++i)
            gl16(abase + (size_t)k0 * 32768 + (wv * 2 + i) * 1024 + lane * 16,
                 au[k0] + (wv * 2 + i) * 1024);

    asm volatile("s_waitcnt vmcnt(0)" ::: "memory");
    __builtin_amdgcn_sched_barrier(0);
    __builtin_amdgcn_s_barrier();
    __builtin_amdgcn_sched_barrier(0);

    f32x4 acc[4][4] = {};
    const int aoff = oh * 4096 + lo * 64 + hi * 16;   // wave's byte base in au[]

    #pragma unroll
    for (int kh = 0; kh < 3; ++kh) {
        #pragma unroll
        for (int kw = 0; kw < 3; ++kw) {
            const int kpos = kh * 3 + kw;
            if (kpos < 7) {
                #pragma unroll
                for (int i = 0; i < 2; ++i)
                    gl16(abase + (size_t)(kpos + 2) * 32768 + (wv * 2 + i) * 1024
                             + lane * 16,
                         au[(kpos + 2) % 3] + (wv * 2 + i) * 1024);
                asm volatile("s_waitcnt vmcnt(4)" ::: "memory");
            } else if (kpos == 7) {
                asm volatile("s_waitcnt vmcnt(2)" ::: "memory");
            } else {
                asm volatile("s_waitcnt vmcnt(0)" ::: "memory");
            }
            __builtin_amdgcn_sched_barrier(0);
            __builtin_amdgcn_s_barrier();
            __builtin_amdgcn_sched_barrier(0);

            const char* ab = au[kpos % 3];
            short8 bf0, bf1, bf2, bf3;
            #pragma unroll
            for (int nt = 0; nt < 4; ++nt) {
                int g = nt * 16 + lo + kw;                 // padded col 0..65
                short8 bf = *(const short8*)(tl + ((lr + kh) * 80 + g) * 32
                                                + ((hi ^ (g & 3)) << 3));
                if (nt == 0) bf0 = bf; else if (nt == 1) bf1 = bf;
                else if (nt == 2) bf2 = bf; else bf3 = bf;
            }
            #pragma unroll
            for (int mt = 0; mt < 4; ++mt) {
                short8 af = *(const short8*)(ab + mt * 1024 + aoff);
                acc[mt][0] = __builtin_amdgcn_mfma_f32_16x16x32_bf16(af, bf0, acc[mt][0], 0, 0, 0);
                acc[mt][1] = __builtin_amdgcn_mfma_f32_16x16x32_bf16(af, bf1, acc[mt][1], 0, 0, 0);
                acc[mt][2] = __builtin_amdgcn_mfma_f32_16x16x32_bf16(af, bf2, acc[mt][2], 0, 0, 0);
                acc[mt][3] = __builtin_amdgcn_mfma_f32_16x16x32_bf16(af, bf3, acc[mt][3], 0, 0, 0);
            }
            __builtin_amdgcn_sched_barrier(0);
            __builtin_amdgcn_s_barrier();
        }
    }

    int h = R0 + lr;
    #pragma unroll
    for (int mt = 0; mt < 4; ++mt) {
        f32x4 bu4 = *(const f32x4*)(bu + Ob + mt * 16 + hi * 4);
        #pragma unroll
        for (int nt = 0; nt < 4; ++nt) {
            int px = nt * 16 + lo;
            #pragma unroll
            for (int j = 0; j < 4; ++j) {
                int O = Ob + mt * 16 + hi * 4 + j;
                size_t gidx = (((size_t)(b * 512 + O) * 64) + h) * 64 + px;
                out[gidx] = acc[mt][nt][j] + content[gidx] + bu4[j];
            }
        }
    }
}

// ---------------------------------------------------------------------------
extern "C" void kernel_launch(void* const* d_in, const int* in_sizes, int n_in,
                              void* d_out, int out_size, void* d_ws, size_t ws_size,
                              hipStream_t stream) {
    const float* content = (const float*)d_in[0];
    const float* f1      = (const float*)d_in[1];
    const float* f2      = (const float*)d_in[2];
    const float* wd      = (const float*)d_in[3];
    const float* bd      = (const float*)d_in[4];
    const float* wu      = (const float*)d_in[5];
    const float* bu      = (const float*)d_in[6];
    float* out = (float*)d_out;

    char* ws = (char*)d_ws;
    // layout (bytes):
    //   xTc    [8][8][66][66][64] bf16 : 35,684,352
    //   wd_frag                        :  2,359,296
    //   wu_frag                        :  2,359,296
    //   bd_eff                         :      1,024
    //   tp2    [8][66][80][32] bf16    :  2,703,360   (total ~43.1 MiB)
    short* xTc     = (short*)(ws);
    short* wd_frag = (short*)(ws + 35684352);
    short* wu_frag = (short*)(ws + 38043648);
    float* bd_eff  = (float*)(ws + 40402944);
    short* tp2     = (short*)(ws + 40403968);

    k_prep     <<<dim3(2090), dim3(256), 0, stream>>>(content, f1, f2, wd, bd, wu,
                                                      xTc, wd_frag, wu_frag,
                                                      bd_eff, tp2);
    k_conv_down<<<dim3(256),  dim3(512), 0, stream>>>((const char*)xTc,
                                                      (const char*)wd_frag,
                                                      bd_eff, tp2);
    k_conv_up  <<<dim3(1024), dim3(256), 0, stream>>>(tp2, wu_frag, content, bu, out);
}

// Round 18
// 73.823 us; speedup vs baseline: 1.0580x; 1.0334x over previous
//
#include <hip/hip_runtime.h>
#include <hip/hip_bf16.h>

typedef __attribute__((ext_vector_type(8)))  short short8;
typedef __attribute__((ext_vector_type(4)))  short short4v;
typedef __attribute__((ext_vector_type(4)))  float f32x4;

static __device__ inline short f2bf(float f) {
    union { __hip_bfloat16 h; unsigned short u; } cv;
    cv.h = __float2bfloat16(f);
    return (short)cv.u;
}

typedef __attribute__((address_space(3))) void lds_void;
typedef const __attribute__((address_space(1))) void glob_void;
static __device__ inline void gl16(const void* g, void* l) {
    // global -> LDS direct copy, 16 B/lane (1 KiB/wave). LDS dest must be
    // wave-uniform base (+ lane*16 HW-added); global src is per-lane.
    __builtin_amdgcn_global_load_lds((glob_void*)g, (lds_void*)l, 16, 0, 0);
}

// ---------------------------------------------------------------------------
// Kernel 1: k_prep — ALL prep work in ONE dispatch (unchanged from R17).
//   blocks [0,512)     : transpose (fat, 8 tiles each, reg-staged pipeline)
//   blocks [512,1024)  : fold1 -> wd_frag
//   blocks [1024,1536) : fold2 -> wu_frag
//   blocks [1536,2056) : zero halo of xTc
//   blocks [2056,2089) : zero halo of tp2
//   block  2089        : bd_eff
// ---------------------------------------------------------------------------
__global__ __launch_bounds__(256) void k_prep(const float* __restrict__ x,
                                              const float* __restrict__ f1,
                                              const float* __restrict__ f2,
                                              const float* __restrict__ wd,
                                              const float* __restrict__ bd,
                                              const float* __restrict__ wu,
                                              short* __restrict__ xTc,
                                              short* __restrict__ wd_frag,
                                              short* __restrict__ wu_frag,
                                              float* __restrict__ bd_eff,
                                              short* __restrict__ tp2) {
    __shared__ float lds[64][65];     // 16.6 KB -> 8 blocks/CU
    int blk = blockIdx.x;
    int t = threadIdx.x;

    if (blk < 512) {
        // ---- transpose role: fat block = (b, h); loop cbq = 0..7 ----
        int h = blk & 63, b = blk >> 6;
        int cr = t >> 4, wq = t & 15;          // row-within-16, 4-float group
        const float* xb = x + ((size_t)h) * 64 + (size_t)wq * 4;
        f32x4 r0, r1, r2, r3;
        {
            const float* p = xb + ((size_t)(b * 512) + cr) * 4096;
            r0 = *(const f32x4*)(p);
            r1 = *(const f32x4*)(p + 16 * 4096);
            r2 = *(const f32x4*)(p + 32 * 4096);
            r3 = *(const f32x4*)(p + 48 * 4096);
        }
        for (int cb = 0; cb < 8; ++cb) {
            asm volatile("s_waitcnt vmcnt(0)" ::: "memory");
            __builtin_amdgcn_sched_barrier(0);
            lds[ 0 + cr][wq * 4 + 0] = r0.x; lds[ 0 + cr][wq * 4 + 1] = r0.y;
            lds[ 0 + cr][wq * 4 + 2] = r0.z; lds[ 0 + cr][wq * 4 + 3] = r0.w;
            lds[16 + cr][wq * 4 + 0] = r1.x; lds[16 + cr][wq * 4 + 1] = r1.y;
            lds[16 + cr][wq * 4 + 2] = r1.z; lds[16 + cr][wq * 4 + 3] = r1.w;
            lds[32 + cr][wq * 4 + 0] = r2.x; lds[32 + cr][wq * 4 + 1] = r2.y;
            lds[32 + cr][wq * 4 + 2] = r2.z; lds[32 + cr][wq * 4 + 3] = r2.w;
            lds[48 + cr][wq * 4 + 0] = r3.x; lds[48 + cr][wq * 4 + 1] = r3.y;
            lds[48 + cr][wq * 4 + 2] = r3.z; lds[48 + cr][wq * 4 + 3] = r3.w;
            if (cb < 7) {
                const float* p = xb + ((size_t)(b * 512 + (cb + 1) * 64) + cr) * 4096;
                r0 = *(const f32x4*)(p);
                r1 = *(const f32x4*)(p + 16 * 4096);
                r2 = *(const f32x4*)(p + 32 * 4096);
                r3 = *(const f32x4*)(p + 48 * 4096);
            }
            asm volatile("s_waitcnt lgkmcnt(0)" ::: "memory");
            __builtin_amdgcn_sched_barrier(0);
            __builtin_amdgcn_s_barrier();
            __builtin_amdgcn_sched_barrier(0);
            #pragma unroll
            for (int k = 0; k < 2; ++k) {
                int j = k * 256 + t;
                int sl = j & 7;
                int wl = (j >> 3) & 7;
                int wh = j >> 6;                 // wave-uniform
                int w = wh * 8 + wl;
                short8 v;
                #pragma unroll
                for (int e = 0; e < 8; ++e) v[e] = f2bf(lds[sl * 8 + e][w]);
                int slotp = sl ^ ((w + 1) & 7);
                *(short8*)(xTc + (((size_t)(b * 8 + cb) * 66 + (h + 1)) * 66 + (w + 1)) * 64
                               + slotp * 8) = v;
            }
            __builtin_amdgcn_s_barrier();       // reads done before next writes
        }
    } else if (blk < 1024) {
        // ---- fold1 role: wd_frag[b][ci16][kpos9][mt2][512], lane-linear ----
        int id = (blk - 512) * 256 + t;
        int i = id & 511;
        int o = (id >> 9) & 31;
        int b = id >> 14;
        float acc[9];
        #pragma unroll
        for (int k = 0; k < 9; ++k) acc[k] = 0.f;
        for (int m = 0; m < 32; ++m) {
            float f = f1[(b * 32 + o) * 32 + m];
            const float* wrow = wd + ((size_t)m * 512 + i) * 9;
            #pragma unroll
            for (int k = 0; k < 9; ++k) acc[k] += f * wrow[k];
        }
        int ci = i >> 5, hi = (i >> 3) & 3, e = i & 7;
        int mt = o >> 4, lo = o & 15;
        #pragma unroll
        for (int k = 0; k < 9; ++k)
            wd_frag[(((size_t)(b * 16 + ci) * 9 + k) * 2 + mt) * 512
                    + hi * 128 + lo * 8 + e] = f2bf(acc[k]);
    } else if (blk < 1536) {
        // ---- fold2 role: wu_frag[b][kpos9][g32][512] ----
        int id = (blk - 1024) * 256 + t;
        int c = id & 31;
        int O = (id >> 5) & 511;
        int b = id >> 14;
        float acc[9];
        #pragma unroll
        for (int k = 0; k < 9; ++k) acc[k] = 0.f;
        for (int m = 0; m < 32; ++m) {
            float f = f2[(b * 32 + m) * 32 + c];
            const float* wr = wu + ((size_t)O * 32 + m) * 9;
            #pragma unroll
            for (int k = 0; k < 9; ++k) acc[k] += wr[k] * f;
        }
        int g = O >> 4, lo = O & 15, hi = c >> 3, e = c & 7;
        #pragma unroll
        for (int k = 0; k < 9; ++k)
            wu_frag[((size_t)(b * 9 + k) * 32 + g) * 512 + lo * 32 + hi * 8 + e]
                = f2bf(acc[k]);
    } else if (blk < 2056) {
        // ---- zero halo of xTc: [64 img][66][66][64] ----
        int id = (blk - 1536) * 256 + t;
        if (id < 64 * 260 * 8) {
            int c8 = id % 8;
            int rest = id / 8;
            int px = rest % 260;
            int img = rest / 260;
            int row, col;
            if (px < 66)       { row = 0;  col = px; }
            else if (px < 132) { row = 65; col = px - 66; }
            else { int q = px - 132; row = 1 + (q >> 1); col = (q & 1) ? 65 : 0; }
            short8 z = {0, 0, 0, 0, 0, 0, 0, 0};
            *(short8*)(xTc + ((size_t)(img * 66 + row) * 66 + col) * 64 + c8 * 8) = z;
        }
    } else if (blk < 2089) {
        // ---- zero halo of tp2: [8 img][66][80][32] ----
        int id = (blk - 2056) * 256 + t;
        if (id < 8 * 260 * 4) {
            int c8 = id % 4;
            int rest = id / 4;
            int px = rest % 260;
            int img = rest / 260;
            int row, col;
            if (px < 66)       { row = 0;  col = px; }
            else if (px < 132) { row = 65; col = px - 66; }
            else { int q = px - 132; row = 1 + (q >> 1); col = (q & 1) ? 65 : 0; }
            short8 z = {0, 0, 0, 0, 0, 0, 0, 0};
            *(short8*)(tp2 + ((size_t)(img * 66 + row) * 80 + col) * 32 + c8 * 8) = z;
        }
    } else {
        // ---- bd role ----
        int b = t >> 5, o = t & 31;
        float acc = 0.f;
        #pragma unroll
        for (int m = 0; m < 32; ++m) acc += f1[(b * 32 + o) * 32 + m] * bd[m];
        bd_eff[t] = acc;
    }
}

// ---------------------------------------------------------------------------
// Kernel 2: conv_down, K-split pipelined (unchanged from R10/R11).
// ---------------------------------------------------------------------------
__global__ __launch_bounds__(512) void k_conv_down(const char* __restrict__ xTc,
                                                   const char* __restrict__ wd_frag,
                                                   const float* __restrict__ bd_eff,
                                                   short* __restrict__ tp2) {
    __shared__ __align__(16) char xs[2][2][16896];   // [ks][buf][4r x 66c x 64B]
    __shared__ __align__(16) char as_[2][2][18432];  // [ks][buf][9 kpos][2 mt][1KB]
    int d = blockIdx.x;                // 256
    int nb = (d & 7) * 32 + (d >> 3);  // XCD <-> batch swizzle
    int b = nb >> 5, rp = nb & 31;
    int R0 = rp * 2;
    int t = threadIdx.x, lane = t & 63, wv = t >> 6;   // wv 0..7
    int ks = wv >> 2, lr = (wv >> 1) & 1, colh = wv & 1;
    int lo = lane & 15, hi = lane >> 4;

    const char* wdb = wd_frag + (size_t)(b * 16) * 18432;
    const char* xbb = xTc + (size_t)(b * 8) * 557568;

#define STAGE_CD(ci, bf)                                                         \
    {                                                                            \
        const int cc0 = (ci);                                                    \
        const int half4 = (cc0 & 1) * 4;                                         \
        const char* xpl0 = xbb + (size_t)(cc0 >> 1) * 557568;                    \
        const char* xpl1 = xpl0 + (size_t)4 * 557568;                            \
        const char* apl0 = wdb + (size_t)cc0 * 18432;                            \
        const char* apl1 = apl0 + (size_t)8 * 18432;                             \
        _Pragma("unroll")                                                        \
        for (int i2 = 0; i2 < 9; ++i2) {                                         \
            int j = wv * 9 + i2;                                                 \
            if (j >= 70) j -= 70;                                                \
            if (j < 34) {                       /* x job */                      \
                int kss = (j >= 17);                                             \
                int jj = kss ? j - 17 : j;                                       \
                int off = (jj < 16) ? jj * 1024 : 15872;                         \
                int dd = off + (lane << 4);                                      \
                int r = dd / 4224;                                               \
                int rem = dd - r * 4224;                                         \
                int col = rem >> 6;                                              \
                int s4 = (rem >> 4) & 3;                                         \
                int slot = (half4 + (s4 ^ ((col >> 1) & 3))) ^ (col & 7);        \
                gl16((kss ? xpl1 : xpl0)                                         \
                         + ((size_t)(R0 + r) * 66 + col) * 128 + (slot << 4),    \
                     xs[kss][bf] + off);                                         \
            } else {                            /* A job */                      \
                int kss = (j >= 52);                                             \
                int jj = kss ? j - 52 : j - 34;                                  \
                gl16((kss ? apl1 : apl0) + jj * 1024 + (lane << 4),              \
                     as_[kss][bf] + jj * 1024);                                  \
            }                                                                    \
        }                                                                        \
    }

    f32x4 acc[2][2] = {};

    STAGE_CD(0, 0);

    #pragma unroll
    for (int ci = 0; ci < 8; ++ci) {
        int bf = ci & 1;
        if (ci < 7) {
            STAGE_CD(ci + 1, bf ^ 1);
            asm volatile("s_waitcnt vmcnt(9)" ::: "memory");
        } else {
            asm volatile("s_waitcnt vmcnt(0)" ::: "memory");
        }
        __builtin_amdgcn_sched_barrier(0);
        __builtin_amdgcn_s_barrier();
        __builtin_amdgcn_sched_barrier(0);

        const char* xb = xs[ks][bf];
        const char* ab = as_[ks][bf];
        #pragma unroll
        for (int kh = 0; kh < 3; ++kh) {
            #pragma unroll
            for (int kw = 0; kw < 3; ++kw) {
                const int kpos = kh * 3 + kw;
                short8 a0 = *(const short8*)(ab + (kpos * 2 + 0) * 1024 + (lane << 4));
                short8 a1 = *(const short8*)(ab + (kpos * 2 + 1) * 1024 + (lane << 4));
                int row = lr + kh;
                int g0 = colh * 32 + lo + kw;
                int g1 = g0 + 16;
                short8 b0 = *(const short8*)(xb + ((row * 66 + g0) << 6)
                                                + ((hi ^ ((g0 >> 1) & 3)) << 4));
                short8 b1 = *(const short8*)(xb + ((row * 66 + g1) << 6)
                                                + ((hi ^ ((g1 >> 1) & 3)) << 4));
                acc[0][0] = __builtin_amdgcn_mfma_f32_16x16x32_bf16(a0, b0, acc[0][0], 0, 0, 0);
                acc[0][1] = __builtin_amdgcn_mfma_f32_16x16x32_bf16(a0, b1, acc[0][1], 0, 0, 0);
                acc[1][0] = __builtin_amdgcn_mfma_f32_16x16x32_bf16(a1, b0, acc[1][0], 0, 0, 0);
                acc[1][1] = __builtin_amdgcn_mfma_f32_16x16x32_bf16(a1, b1, acc[1][1], 0, 0, 0);
            }
        }
        __builtin_amdgcn_sched_barrier(0);
        __builtin_amdgcn_s_barrier();
    }
#undef STAGE_CD

    // cross-wave K-reduce via LDS scratch (all gl16 drained by peeled vmcnt(0)).
    char* scr = &xs[1][0][0];
    if (ks == 1) {
        char* p = scr + (wv & 3) * 4096 + lane * 64;
        *(f32x4*)(p +  0) = acc[0][0];
        *(f32x4*)(p + 16) = acc[0][1];
        *(f32x4*)(p + 32) = acc[1][0];
        *(f32x4*)(p + 48) = acc[1][1];
    }
    __syncthreads();
    if (ks == 0) {
        const char* p = scr + (wv & 3) * 4096 + lane * 64;
        acc[0][0] += *(const f32x4*)(p +  0);
        acc[0][1] += *(const f32x4*)(p + 16);
        acc[1][0] += *(const f32x4*)(p + 32);
        acc[1][1] += *(const f32x4*)(p + 48);

        int h = R0 + lr;
        #pragma unroll
        for (int nt = 0; nt < 2; ++nt) {
            int colp = colh * 32 + nt * 16 + lo + 1;
            short* ob = tp2 + ((size_t)(b * 66 + h + 1) * 80 + colp) * 32;
            #pragma unroll
            for (int mt = 0; mt < 2; ++mt) {
                f32x4 bd4 = *(const f32x4*)(bd_eff + b * 32 + mt * 16 + hi * 4);
                short4v sv;
                #pragma unroll
                for (int j = 0; j < 4; ++j) {
                    float f = acc[mt][nt][j] + bd4[j];
                    f = f > 0.f ? f : 0.2f * f;
                    sv[j] = f2bf(f);
                }
                int sl = mt * 2 + (hi >> 1);
                int slp = sl ^ (colp & 3);
                *(short4v*)(ob + slp * 8 + (hi & 1) * 4) = sv;
            }
        }
    }
}

// ---------------------------------------------------------------------------
// Kernel 3: conv_up + residual. RESIDUAL FROM xTc (bf16, L3-resident) —
// removes conv_up's 64MB f32 content read from HBM (R18 lever). The lane's
// 4 och (j=0..3) are one aligned 8B short4v in xTc's swizzled slot:
// cs = ocq*2+oh (uniform), slot = mt*2+(hi>>1), offset (hi&1)*4.
// Extra error <= 1/2 ulp bf16 (<=0.016 for |content|<8): absmax <= 0.047.
// ---------------------------------------------------------------------------
__global__ __launch_bounds__(256, 3) void k_conv_up(const short* __restrict__ tp2,
                                                    const short* __restrict__ wu_frag,
                                                    const short* __restrict__ xTc,
                                                    const float* __restrict__ bu,
                                                    float* __restrict__ out) {
    __shared__ __align__(16) short tl[10240];     // 4 x 80 x 32
    __shared__ __align__(16) char au[3][8192];    // [buf][8 g][1KB frag]
    int d = blockIdx.x;                 // 1024
    int nb = (d & 7) * 128 + (d >> 3);  // XCD x <-> batch x
    int b = nb >> 7, ocq = (nb >> 5) & 3, hb = nb & 31;
    int t = threadIdx.x, lane = t & 63, wv = t >> 6;
    int lr = wv >> 1, oh = wv & 1;
    int lo = lane & 15, hi = lane >> 4;
    int Ob = ocq * 128 + oh * 64;
    int R0 = 2 * hb;

    const char* sbase = (const char*)tp2 + ((size_t)(b * 66 + R0) * 80) * 64;
    #pragma unroll
    for (int i = 0; i < 5; ++i)
        gl16(sbase + (wv * 5 + i) * 1024 + lane * 16, (char*)tl + (wv * 5 + i) * 1024);

    // A source: g-frags [ocq*8 .. ocq*8+8) per kpos; kpos stride = 32 KB.
    const char* abase = (const char*)wu_frag + ((size_t)(b * 9) * 32 + ocq * 8) * 1024;
    #pragma unroll
    for (int k0 = 0; k0 < 2; ++k0)        // prologue: stage A[0], A[1]
        #pragma unroll
        for (int i = 0; i < 2; ++i)
            gl16(abase + (size_t)k0 * 32768 + (wv * 2 + i) * 1024 + lane * 16,
                 au[k0] + (wv * 2 + i) * 1024);

    asm volatile("s_waitcnt vmcnt(0)" ::: "memory");
    __builtin_amdgcn_sched_barrier(0);
    __builtin_amdgcn_s_barrier();
    __builtin_amdgcn_sched_barrier(0);

    f32x4 acc[4][4] = {};
    const int aoff = oh * 4096 + lo * 64 + hi * 16;   // wave's byte base in au[]

    #pragma unroll
    for (int kh = 0; kh < 3; ++kh) {
        #pragma unroll
        for (int kw = 0; kw < 3; ++kw) {
            const int kpos = kh * 3 + kw;
            if (kpos < 7) {
                #pragma unroll
                for (int i = 0; i < 2; ++i)
                    gl16(abase + (size_t)(kpos + 2) * 32768 + (wv * 2 + i) * 1024
                             + lane * 16,
                         au[(kpos + 2) % 3] + (wv * 2 + i) * 1024);
                asm volatile("s_waitcnt vmcnt(4)" ::: "memory");
            } else if (kpos == 7) {
                asm volatile("s_waitcnt vmcnt(2)" ::: "memory");
            } else {
                asm volatile("s_waitcnt vmcnt(0)" ::: "memory");
            }
            __builtin_amdgcn_sched_barrier(0);
            __builtin_amdgcn_s_barrier();
            __builtin_amdgcn_sched_barrier(0);

            const char* ab = au[kpos % 3];
            short8 bf0, bf1, bf2, bf3;
            #pragma unroll
            for (int nt = 0; nt < 4; ++nt) {
                int g = nt * 16 + lo + kw;                 // padded col 0..65
                short8 bf = *(const short8*)(tl + ((lr + kh) * 80 + g) * 32
                                                + ((hi ^ (g & 3)) << 3));
                if (nt == 0) bf0 = bf; else if (nt == 1) bf1 = bf;
                else if (nt == 2) bf2 = bf; else bf3 = bf;
            }
            #pragma unroll
            for (int mt = 0; mt < 4; ++mt) {
                short8 af = *(const short8*)(ab + mt * 1024 + aoff);
                acc[mt][0] = __builtin_amdgcn_mfma_f32_16x16x32_bf16(af, bf0, acc[mt][0], 0, 0, 0);
                acc[mt][1] = __builtin_amdgcn_mfma_f32_16x16x32_bf16(af, bf1, acc[mt][1], 0, 0, 0);
                acc[mt][2] = __builtin_amdgcn_mfma_f32_16x16x32_bf16(af, bf2, acc[mt][2], 0, 0, 0);
                acc[mt][3] = __builtin_amdgcn_mfma_f32_16x16x32_bf16(af, bf3, acc[mt][3], 0, 0, 0);
            }
            __builtin_amdgcn_sched_barrier(0);
            __builtin_amdgcn_s_barrier();
        }
    }

    int h = R0 + lr;
    // residual source: xTc plane cs = ocq*2+oh (wave-uniform), row h+1
    const short* xrow = xTc + ((size_t)((b * 8 + ocq * 2 + oh) * 66 + (h + 1)) * 66) * 64;
    #pragma unroll
    for (int mt = 0; mt < 4; ++mt) {
        f32x4 bu4 = *(const f32x4*)(bu + Ob + mt * 16 + hi * 4);
        int slot = mt * 2 + (hi >> 1);
        #pragma unroll
        for (int nt = 0; nt < 4; ++nt) {
            int px = nt * 16 + lo;
            int colp = px + 1;
            short4v cv = *(const short4v*)(xrow + (size_t)colp * 64
                                           + ((slot ^ (colp & 7)) << 3) + (hi & 1) * 4);
            #pragma unroll
            for (int j = 0; j < 4; ++j) {
                int O = Ob + mt * 16 + hi * 4 + j;
                size_t gidx = (((size_t)(b * 512 + O) * 64) + h) * 64 + px;
                union { float f; unsigned u; } r;
                r.u = ((unsigned)(unsigned short)cv[j]) << 16;   // bf16 -> f32
                out[gidx] = acc[mt][nt][j] + r.f + bu4[j];
            }
        }
    }
}

// ---------------------------------------------------------------------------
extern "C" void kernel_launch(void* const* d_in, const int* in_sizes, int n_in,
                              void* d_out, int out_size, void* d_ws, size_t ws_size,
                              hipStream_t stream) {
    const float* content = (const float*)d_in[0];
    const float* f1      = (const float*)d_in[1];
    const float* f2      = (const float*)d_in[2];
    const float* wd      = (const float*)d_in[3];
    const float* bd      = (const float*)d_in[4];
    const float* wu      = (const float*)d_in[5];
    const float* bu      = (const float*)d_in[6];
    float* out = (float*)d_out;

    char* ws = (char*)d_ws;
    // layout (bytes):
    //   xTc    [8][8][66][66][64] bf16 : 35,684,352
    //   wd_frag                        :  2,359,296
    //   wu_frag                        :  2,359,296
    //   bd_eff                         :      1,024
    //   tp2    [8][66][80][32] bf16    :  2,703,360   (total ~43.1 MiB)
    short* xTc     = (short*)(ws);
    short* wd_frag = (short*)(ws + 35684352);
    short* wu_frag = (short*)(ws + 38043648);
    float* bd_eff  = (float*)(ws + 40402944);
    short* tp2     = (short*)(ws + 40403968);

    k_prep     <<<dim3(2090), dim3(256), 0, stream>>>(content, f1, f2, wd, bd, wu,
                                                      xTc, wd_frag, wu_frag,
                                                      bd_eff, tp2);
    k_conv_down<<<dim3(256),  dim3(512), 0, stream>>>((const char*)xTc,
                                                      (const char*)wd_frag,
                                                      bd_eff, tp2);
    k_conv_up  <<<dim3(1024), dim3(256), 0, stream>>>(tp2, wu_frag, xTc, bu, out);
}